// Round 1
// baseline (855.730 us; speedup 1.0000x reference)
//
#include <hip/hip_runtime.h>

typedef float v4f __attribute__((ext_vector_type(4)));

#define EMB    512
#define NSEQ   2048
#define NBATCH 4
#define NHEAD  8
#define HDIM   64
#define MROWS  (NBATCH * NSEQ)   // 8192

// ---------------------------------------------------------------------------
// GEMM: C[M x 512] = A[M x 512] * W[512 x 512]^T + bias
// 64x64 block tile, BK=16, 256 threads, 4x4 micro-tile per thread.
// LDS tiles stored transposed [k][m] so compute reads are contiguous float4.
// ---------------------------------------------------------------------------
__global__ __launch_bounds__(256)
void gemm_bias_nt(const float* __restrict__ A, const float* __restrict__ W,
                  const float* __restrict__ bias, float* __restrict__ C) {
    __shared__ float As[16][64];   // [k][m]
    __shared__ float Ws[16][64];   // [k][n]
    const int tid = threadIdx.x;
    const int m0 = blockIdx.x * 64;
    const int n0 = blockIdx.y * 64;
    const int tm = (tid & 15) * 4;   // 16 groups cover 64 rows
    const int tn = (tid >> 4) * 4;   // 16 groups cover 64 cols
    const int lr = tid >> 2;         // loader row 0..63
    const int lc = (tid & 3) * 4;    // loader k-col {0,4,8,12}

    v4f acc[4];
#pragma unroll
    for (int i = 0; i < 4; ++i) acc[i] = (v4f){0.f, 0.f, 0.f, 0.f};

    for (int kt = 0; kt < EMB; kt += 16) {
        v4f a = *(const v4f*)&A[(size_t)(m0 + lr) * EMB + kt + lc];
        v4f w = *(const v4f*)&W[(size_t)(n0 + lr) * EMB + kt + lc];
        __syncthreads();   // previous compute done before overwrite
#pragma unroll
        for (int j = 0; j < 4; ++j) { As[lc + j][lr] = a[j]; Ws[lc + j][lr] = w[j]; }
        __syncthreads();
#pragma unroll
        for (int k = 0; k < 16; ++k) {
            v4f av = *(const v4f*)&As[k][tm];
            v4f wv = *(const v4f*)&Ws[k][tn];
#pragma unroll
            for (int i = 0; i < 4; ++i) acc[i] += av[i] * wv;
        }
    }
    v4f b4 = *(const v4f*)&bias[n0 + tn];
#pragma unroll
    for (int i = 0; i < 4; ++i) {
        v4f o = acc[i] + b4;
        *(v4f*)&C[(size_t)(m0 + tm + i) * EMB + n0 + tn] = o;
    }
}

// ---------------------------------------------------------------------------
// Flash-style attention, fp32. One block per (b, h, 64-query tile).
// Q/K staged transposed [d][row] in LDS -> conflict-free b128 reads in QK^T.
// Energies are tiny (|e/sqrt(512)| < ~1), so no online-max rescale is needed:
// accumulate O += exp(s)*V and l += sum(exp(s)); divide at the end.
// ---------------------------------------------------------------------------
__global__ __launch_bounds__(256)
void attn(const float* __restrict__ Q, const float* __restrict__ K,
          const float* __restrict__ V, float* __restrict__ O) {
    __shared__ float Qt[64][64];   // [d][qrow]
    __shared__ float Kt[64][64];   // [d][krow]
    __shared__ float Vs[64][68];   // [krow][d]  (stride 68 = 16B aligned, spreads banks)
    __shared__ float Ps[64][68];   // [qrow][krow]
    __shared__ float lred[64][17];

    const int tid  = threadIdx.x;
    const int qt   = blockIdx.x;          // query tile 0..31
    const int bh   = blockIdx.y;          // 0..31
    const int b    = bh >> 3;
    const int h    = bh & 7;
    const int row0 = b * NSEQ + qt * 64;  // global row of Q tile (in M = B*N)
    const int col0 = h * HDIM;            // column offset in E

    const int tx  = tid & 15, ty = tid >> 4;
    const int tx4 = tx * 4,  ty4 = ty * 4;
    const int lrow = tid >> 2;            // loader row 0..63
    const int lcol = (tid & 3) * 16;      // loader col {0,16,32,48}

    const float cexp = 0.06375872f;       // log2(e) / sqrt(512)

    // Q tile -> Qt transposed (visibility guaranteed by first in-loop barrier)
#pragma unroll
    for (int s = 0; s < 16; s += 4) {
        v4f q4 = *(const v4f*)&Q[(size_t)(row0 + lrow) * EMB + col0 + lcol + s];
#pragma unroll
        for (int j = 0; j < 4; ++j) Qt[lcol + s + j][lrow] = q4[j];
    }

    v4f o_[4];
#pragma unroll
    for (int i = 0; i < 4; ++i) o_[i] = (v4f){0.f, 0.f, 0.f, 0.f};
    float rsum[4] = {0.f, 0.f, 0.f, 0.f};

    for (int kt = 0; kt < NSEQ / 64; ++kt) {
        const int kbase = b * NSEQ + kt * 64;
        __syncthreads();   // previous PV (and initial Qt writes) complete
#pragma unroll
        for (int s = 0; s < 16; s += 4) {
            v4f k4 = *(const v4f*)&K[(size_t)(kbase + lrow) * EMB + col0 + lcol + s];
#pragma unroll
            for (int j = 0; j < 4; ++j) Kt[lcol + s + j][lrow] = k4[j];
            v4f vv = *(const v4f*)&V[(size_t)(kbase + lrow) * EMB + col0 + lcol + s];
            *(v4f*)&Vs[lrow][lcol + s] = vv;
        }
        __syncthreads();

        // S = Q K^T (raw, unscaled)
        v4f s_[4];
#pragma unroll
        for (int i = 0; i < 4; ++i) s_[i] = (v4f){0.f, 0.f, 0.f, 0.f};
#pragma unroll 16
        for (int kd = 0; kd < 64; ++kd) {
            v4f q4 = *(const v4f*)&Qt[kd][ty4];
            v4f k4 = *(const v4f*)&Kt[kd][tx4];
#pragma unroll
            for (int i = 0; i < 4; ++i) s_[i] += q4[i] * k4;
        }

        // P = exp(S/sqrt(E)), accumulate row sums, stash in LDS
#pragma unroll
        for (int i = 0; i < 4; ++i) {
            v4f p;
#pragma unroll
            for (int j = 0; j < 4; ++j) p[j] = exp2f(s_[i][j] * cexp);
            rsum[i] += p[0] + p[1] + p[2] + p[3];
            *(v4f*)&Ps[ty4 + i][tx4] = p;
        }
        __syncthreads();

        // O += P * V
#pragma unroll 4
        for (int kq = 0; kq < 16; ++kq) {
            v4f p0 = *(const v4f*)&Ps[ty4 + 0][kq * 4];
            v4f p1 = *(const v4f*)&Ps[ty4 + 1][kq * 4];
            v4f p2 = *(const v4f*)&Ps[ty4 + 2][kq * 4];
            v4f p3 = *(const v4f*)&Ps[ty4 + 3][kq * 4];
#pragma unroll
            for (int c = 0; c < 4; ++c) {
                v4f vv = *(const v4f*)&Vs[kq * 4 + c][tx4];
                o_[0] += p0[c] * vv;
                o_[1] += p1[c] * vv;
                o_[2] += p2[c] * vv;
                o_[3] += p3[c] * vv;
            }
        }
    }

    // reduce l across the 16 tx-groups, normalize, store
#pragma unroll
    for (int i = 0; i < 4; ++i) lred[ty4 + i][tx] = rsum[i];
    __syncthreads();
#pragma unroll
    for (int i = 0; i < 4; ++i) {
        float l = 0.f;
#pragma unroll
        for (int t = 0; t < 16; ++t) l += lred[ty4 + i][t];
        v4f o = o_[i] * (1.0f / l);
        *(v4f*)&O[(size_t)(row0 + ty4 + i) * EMB + col0 + tx4] = o;
    }
}

// ---------------------------------------------------------------------------
extern "C" void kernel_launch(void* const* d_in, const int* in_sizes, int n_in,
                              void* d_out, int out_size, void* d_ws, size_t ws_size,
                              hipStream_t stream) {
    const float* x  = (const float*)d_in[0];
    const float* Wq = (const float*)d_in[1];
    const float* bq = (const float*)d_in[2];
    const float* Wk = (const float*)d_in[3];
    const float* bk = (const float*)d_in[4];
    const float* Wv = (const float*)d_in[5];
    const float* bv = (const float*)d_in[6];
    const float* Wo = (const float*)d_in[7];
    const float* bo = (const float*)d_in[8];

    float* Q  = (float*)d_ws;                 // 16.78 MB each
    float* K  = Q + (size_t)MROWS * EMB;
    float* V  = K + (size_t)MROWS * EMB;
    float* O1 = V + (size_t)MROWS * EMB;      // total ws use: 67.1 MB

    dim3 gg(MROWS / 64, EMB / 64), bb(256);
    gemm_bias_nt<<<gg, bb, 0, stream>>>(x,  Wq, bq, Q);
    gemm_bias_nt<<<gg, bb, 0, stream>>>(x,  Wk, bk, K);
    gemm_bias_nt<<<gg, bb, 0, stream>>>(x,  Wv, bv, V);
    attn<<<dim3(NSEQ / 64, NBATCH * NHEAD), bb, 0, stream>>>(Q, K, V, O1);
    gemm_bias_nt<<<gg, bb, 0, stream>>>(O1, Wo, bo, (float*)d_out);
}

// Round 2
// 205.083 us; speedup vs baseline: 4.1726x; 4.1726x over previous
//
#include <hip/hip_runtime.h>

typedef float f32x4 __attribute__((ext_vector_type(4)));
typedef float f32x16 __attribute__((ext_vector_type(16)));
typedef short bf16x8 __attribute__((ext_vector_type(8)));
typedef unsigned int uint;
typedef unsigned short ushort_t;

#define EMB    512
#define NSEQ   2048
#define NBATCH 4
#define NHEAD  8
#define MROWS  (NBATCH * NSEQ)   // 8192

// round-to-nearest-even fp32 -> bf16 (bit trick)
__device__ __forceinline__ uint f2bf(float x) {
    uint u = __builtin_bit_cast(uint, x);
    return (u + 0x7fffu + ((u >> 16) & 1u)) >> 16;
}

// ---------------------------------------------------------------------------
// Prep: x -> bf16; Wq|Wk|Wv -> Wqkvb bf16 [1536][512]; biases concat; Wo -> bf16
// ---------------------------------------------------------------------------
__global__ __launch_bounds__(256)
void prep(const float* __restrict__ x,
          const float* __restrict__ Wq, const float* __restrict__ Wk,
          const float* __restrict__ Wv, const float* __restrict__ Wo,
          const float* __restrict__ bq, const float* __restrict__ bk,
          const float* __restrict__ bv,
          ushort_t* __restrict__ xb, ushort_t* __restrict__ Wqkvb,
          float* __restrict__ bqkv, ushort_t* __restrict__ Wob) {
    int t = blockIdx.x * 256 + threadIdx.x;   // f4-group index, 1048576 total
    {
        float4 v = ((const float4*)x)[t];
        uint2 p;
        p.x = f2bf(v.x) | (f2bf(v.y) << 16);
        p.y = f2bf(v.z) | (f2bf(v.w) << 16);
        ((uint2*)xb)[t] = p;
    }
    if (t < 65536) {   // 512*512/4 groups per weight
        float4 a = ((const float4*)Wq)[t];
        float4 b = ((const float4*)Wk)[t];
        float4 c = ((const float4*)Wv)[t];
        float4 d = ((const float4*)Wo)[t];
        uint2 p;
        p.x = f2bf(a.x) | (f2bf(a.y) << 16); p.y = f2bf(a.z) | (f2bf(a.w) << 16);
        ((uint2*)Wqkvb)[t] = p;
        p.x = f2bf(b.x) | (f2bf(b.y) << 16); p.y = f2bf(b.z) | (f2bf(b.w) << 16);
        ((uint2*)Wqkvb)[t + 65536] = p;
        p.x = f2bf(c.x) | (f2bf(c.y) << 16); p.y = f2bf(c.z) | (f2bf(c.w) << 16);
        ((uint2*)Wqkvb)[t + 131072] = p;
        p.x = f2bf(d.x) | (f2bf(d.y) << 16); p.y = f2bf(d.z) | (f2bf(d.w) << 16);
        ((uint2*)Wob)[t] = p;
    }
    if (t < 512) {
        bqkv[t] = bq[t]; bqkv[512 + t] = bk[t]; bqkv[1024 + t] = bv[t];
    }
}

// ---------------------------------------------------------------------------
// GEMM C[8192 x N] = A[8192x512]bf16 * BT[Nx512]bf16 + bias, 128x128 tile,
// BK=32, 4 waves, 16x16x32 mfma, 4x4 subtiles per wave.
// MODE 0: QKV (N=1536): n0<1024 -> bf16 scalar stores to QKb[8192][1024];
//         n0>=1024 -> transposed packed stores to VTg[2048][2048].
// MODE 1: out proj (N=512): fp32 stores + bias to C[8192][512].
// ---------------------------------------------------------------------------
template<int MODE>
__global__ __launch_bounds__(256)
void gemm128(const ushort_t* __restrict__ A, const ushort_t* __restrict__ BT,
             const float* __restrict__ bias, ushort_t* __restrict__ oQK,
             ushort_t* __restrict__ oVT, float* __restrict__ oC) {
    __shared__ ushort_t As[128][40];
    __shared__ ushort_t Bs[128][40];
    const int tid = threadIdx.x, wave = tid >> 6, lane = tid & 63;
    const int m0 = blockIdx.x * 128, n0 = blockIdx.y * 128;
    const int wr = (wave & 1) * 64, wc = (wave >> 1) * 64;

    f32x4 acc[4][4];
#pragma unroll
    for (int i = 0; i < 4; ++i)
#pragma unroll
        for (int j = 0; j < 4; ++j) acc[i][j] = (f32x4){0.f, 0.f, 0.f, 0.f};

    const int sr = tid >> 1, sh = (tid & 1) * 16;
    const ushort_t* Arow = A + (size_t)(m0 + sr) * 512 + sh;
    const ushort_t* Brow = BT + (size_t)(n0 + sr) * 512 + sh;
    const int fr = lane & 15, fc = (lane >> 4) * 8;

    for (int kt = 0; kt < 16; ++kt) {
        uint4 a0 = *(const uint4*)(Arow + kt * 32);
        uint4 a1 = *(const uint4*)(Arow + kt * 32 + 8);
        uint4 b0 = *(const uint4*)(Brow + kt * 32);
        uint4 b1 = *(const uint4*)(Brow + kt * 32 + 8);
        __syncthreads();
        *(uint4*)&As[sr][sh] = a0;  *(uint4*)&As[sr][sh + 8] = a1;
        *(uint4*)&Bs[sr][sh] = b0;  *(uint4*)&Bs[sr][sh + 8] = b1;
        __syncthreads();
        bf16x8 af[4], bf[4];
#pragma unroll
        for (int i = 0; i < 4; ++i) af[i] = *(const bf16x8*)&As[wr + i * 16 + fr][fc];
#pragma unroll
        for (int j = 0; j < 4; ++j) bf[j] = *(const bf16x8*)&Bs[wc + j * 16 + fr][fc];
#pragma unroll
        for (int i = 0; i < 4; ++i)
#pragma unroll
            for (int j = 0; j < 4; ++j)
                acc[i][j] = __builtin_amdgcn_mfma_f32_16x16x32_bf16(af[i], bf[j], acc[i][j], 0, 0, 0);
    }

    const int col_l = lane & 15, row_l = (lane >> 4) * 4;
#pragma unroll
    for (int j = 0; j < 4; ++j) {
        const int col = n0 + wc + j * 16 + col_l;
        const float bv = bias[col];
#pragma unroll
        for (int i = 0; i < 4; ++i) {
            const int row = m0 + wr + i * 16 + row_l;
            f32x4 v = acc[i][j];
            v += (f32x4){bv, bv, bv, bv};
            if (MODE == 0) {
                if (n0 < 1024) {
#pragma unroll
                    for (int r = 0; r < 4; ++r)
                        oQK[(size_t)(row + r) * 1024 + col] = (ushort_t)f2bf(v[r]);
                } else {
                    const int e = col - 1024;
                    const int b = row >> 11, tok = row & 2047;
                    uint2 p;
                    p.x = f2bf(v[0]) | (f2bf(v[1]) << 16);
                    p.y = f2bf(v[2]) | (f2bf(v[3]) << 16);
                    *(uint2*)&oVT[((size_t)(b * 512 + e)) * 2048 + tok] = p;
                }
            } else {
#pragma unroll
                for (int r = 0; r < 4; ++r)
                    oC[(size_t)(row + r) * 512 + col] = v[r];
            }
        }
    }
}

// ---------------------------------------------------------------------------
// MFMA flash attention (no max-rescale: |logit| < ~1 provably).
// Block = 128 q-rows x (b,h); wave w owns q-rows [w*32, w*32+32), Q frags in
// registers. Per 64-krow tile: S^T = K·Q^T (32x32x16), P^T = exp2(S^T*c) packed
// to LDS b64, O += P·V with V-frags from LDS-staged VTg tile.
// ---------------------------------------------------------------------------
__global__ __launch_bounds__(256)
void attn_mfma(const ushort_t* __restrict__ QK, const ushort_t* __restrict__ VT,
               ushort_t* __restrict__ AO) {
    __shared__ ushort_t Ks[64][72];       // [krow][d]
    __shared__ ushort_t Vs[64][72];       // [d][krow]  (V^T tile)
    __shared__ ushort_t Ps[4][32][72];    // per-wave [qrow][krow]
    __shared__ float ls[128];

    const int tid = threadIdx.x, w = tid >> 6, lane = tid & 63;
    const int qt = blockIdx.x, bh = blockIdx.y, b = bh >> 3, h = bh & 7;
    const int l31 = lane & 31, lhi = lane >> 5;
    const float cexp = 0.06375872f;       // log2(e)/sqrt(512)

    // preload Q B-frags (16 VGPRs), reused across whole K loop
    const size_t qrow = (size_t)(b * NSEQ + qt * 128 + w * 32 + l31);
    bf16x8 qf[4];
#pragma unroll
    for (int ks = 0; ks < 4; ++ks)
        qf[ks] = *(const bf16x8*)&QK[qrow * 1024 + h * 64 + ks * 16 + lhi * 8];

    f32x16 accO[2];
#pragma unroll
    for (int i = 0; i < 16; ++i) { accO[0][i] = 0.f; accO[1][i] = 0.f; }
    float lpart = 0.f;

    const int sr = tid & 63, sc = (tid >> 6) * 16;
    const ushort_t* Kg = QK + (size_t)(b * NSEQ) * 1024 + 512 + h * 64;
    const ushort_t* Vg = VT + ((size_t)(b * 512 + h * 64)) * 2048;

    for (int kt = 0; kt < 32; ++kt) {
        const int k0 = kt * 64;
        uint4 kv0 = *(const uint4*)&Kg[(size_t)(k0 + sr) * 1024 + sc];
        uint4 kv1 = *(const uint4*)&Kg[(size_t)(k0 + sr) * 1024 + sc + 8];
        uint4 vv0 = *(const uint4*)&Vg[(size_t)sr * 2048 + k0 + sc];
        uint4 vv1 = *(const uint4*)&Vg[(size_t)sr * 2048 + k0 + sc + 8];
        __syncthreads();                          // A: prior reads done
        *(uint4*)&Ks[sr][sc] = kv0;  *(uint4*)&Ks[sr][sc + 8] = kv1;
        *(uint4*)&Vs[sr][sc] = vv0;  *(uint4*)&Vs[sr][sc + 8] = vv1;
        __syncthreads();                          // B: tiles visible

        // S^T = K · Q^T : D[m=krow][n=qrow]
        f32x16 st[2];
#pragma unroll
        for (int i = 0; i < 16; ++i) { st[0][i] = 0.f; st[1][i] = 0.f; }
#pragma unroll
        for (int ks = 0; ks < 4; ++ks) {
            bf16x8 ka0 = *(const bf16x8*)&Ks[l31][ks * 16 + lhi * 8];
            bf16x8 ka1 = *(const bf16x8*)&Ks[32 + l31][ks * 16 + lhi * 8];
            st[0] = __builtin_amdgcn_mfma_f32_32x32x16_bf16(ka0, qf[ks], st[0], 0, 0, 0);
            st[1] = __builtin_amdgcn_mfma_f32_32x32x16_bf16(ka1, qf[ks], st[1], 0, 0, 0);
        }

        // P^T = exp2(S^T * c); truncate to bf16, sum truncated values for l
#pragma unroll
        for (int ms = 0; ms < 2; ++ms) {
#pragma unroll
            for (int g = 0; g < 4; ++g) {
                uint u0 = __builtin_bit_cast(uint, exp2f(st[ms][g * 4 + 0] * cexp));
                uint u1 = __builtin_bit_cast(uint, exp2f(st[ms][g * 4 + 1] * cexp));
                uint u2 = __builtin_bit_cast(uint, exp2f(st[ms][g * 4 + 2] * cexp));
                uint u3 = __builtin_bit_cast(uint, exp2f(st[ms][g * 4 + 3] * cexp));
                lpart += __builtin_bit_cast(float, u0 & 0xffff0000u)
                       + __builtin_bit_cast(float, u1 & 0xffff0000u)
                       + __builtin_bit_cast(float, u2 & 0xffff0000u)
                       + __builtin_bit_cast(float, u3 & 0xffff0000u);
                uint2 p;
                p.x = (u0 >> 16) | (u1 & 0xffff0000u);
                p.y = (u2 >> 16) | (u3 & 0xffff0000u);
                *(uint2*)&Ps[w][l31][ms * 32 + g * 8 + lhi * 4] = p;
            }
        }
        __syncthreads();                          // C: P^T visible (cross-lane)

        // O += P · V : D[m=qrow][n=d]
#pragma unroll
        for (int ks = 0; ks < 4; ++ks) {
            bf16x8 pa  = *(const bf16x8*)&Ps[w][l31][ks * 16 + lhi * 8];
            bf16x8 vb0 = *(const bf16x8*)&Vs[l31][ks * 16 + lhi * 8];
            bf16x8 vb1 = *(const bf16x8*)&Vs[32 + l31][ks * 16 + lhi * 8];
            accO[0] = __builtin_amdgcn_mfma_f32_32x32x16_bf16(pa, vb0, accO[0], 0, 0, 0);
            accO[1] = __builtin_amdgcn_mfma_f32_32x32x16_bf16(pa, vb1, accO[1], 0, 0, 0);
        }
    }

    // finalize l (halves split by lane>>5), broadcast per-row via LDS
    float lfull = lpart + __shfl_xor(lpart, 32);
    if (lane < 32) ls[w * 32 + l31] = lfull;
    __syncthreads();

#pragma unroll
    for (int g = 0; g < 4; ++g) {
        float4 lv = *(const float4*)&ls[w * 32 + g * 8 + lhi * 4];
#pragma unroll
        for (int r = 0; r < 4; ++r) {
            const float inv = 1.0f / ((const float*)&lv)[r];
            const int rowp = g * 8 + lhi * 4 + r;
            const size_t orow = (size_t)(b * NSEQ + qt * 128 + w * 32 + rowp);
            AO[orow * 512 + h * 64 + l31]      = (ushort_t)f2bf(accO[0][g * 4 + r] * inv);
            AO[orow * 512 + h * 64 + 32 + l31] = (ushort_t)f2bf(accO[1][g * 4 + r] * inv);
        }
    }
}

// ---------------------------------------------------------------------------
extern "C" void kernel_launch(void* const* d_in, const int* in_sizes, int n_in,
                              void* d_out, int out_size, void* d_ws, size_t ws_size,
                              hipStream_t stream) {
    const float* x  = (const float*)d_in[0];
    const float* Wq = (const float*)d_in[1];
    const float* bq = (const float*)d_in[2];
    const float* Wk = (const float*)d_in[3];
    const float* bk = (const float*)d_in[4];
    const float* Wv = (const float*)d_in[5];
    const float* bv = (const float*)d_in[6];
    const float* Wo = (const float*)d_in[7];
    const float* bo = (const float*)d_in[8];

    char* ws = (char*)d_ws;
    ushort_t* xb    = (ushort_t*)(ws);                       // 8,388,608 B
    ushort_t* Wqkvb = (ushort_t*)(ws + 8388608);             // 1,572,864 B
    ushort_t* Wob   = (ushort_t*)(ws + 9961472);             //   524,288 B
    float*    bqkv  = (float*)   (ws + 10485760);            //     6,144 B
    ushort_t* QKb   = (ushort_t*)(ws + 10491904);            // 16,777,216 B
    ushort_t* VTg   = (ushort_t*)(ws + 27269120);            // 8,388,608 B
    ushort_t* AOb   = (ushort_t*)(ws + 35657728);            // 8,388,608 B

    prep<<<4096, 256, 0, stream>>>(x, Wq, Wk, Wv, Wo, bq, bk, bv,
                                   xb, Wqkvb, bqkv, Wob);
    gemm128<0><<<dim3(64, 12), 256, 0, stream>>>(xb, Wqkvb, bqkv, QKb, VTg, nullptr);
    attn_mfma<<<dim3(16, 32), 256, 0, stream>>>(QKb, VTg, AOb);
    gemm128<1><<<dim3(64, 4), 256, 0, stream>>>(AOb, Wob, bo, nullptr, nullptr, (float*)d_out);
}

// Round 3
// 194.864 us; speedup vs baseline: 4.3914x; 1.0524x over previous
//
#include <hip/hip_runtime.h>

typedef float f32x4 __attribute__((ext_vector_type(4)));
typedef float f32x16 __attribute__((ext_vector_type(16)));
typedef short bf16x8 __attribute__((ext_vector_type(8)));
typedef unsigned int uint;
typedef unsigned short ushort_t;

#define EMB    512
#define NSEQ   2048
#define NBATCH 4
#define NHEAD  8
#define MROWS  (NBATCH * NSEQ)   // 8192
#define CEXP   0.06375872f       // log2(e) / sqrt(512)

// round-to-nearest-even fp32 -> bf16 (bit trick)
__device__ __forceinline__ uint f2bf(float x) {
    uint u = __builtin_bit_cast(uint, x);
    return (u + 0x7fffu + ((u >> 16) & 1u)) >> 16;
}

// ---------------------------------------------------------------------------
// Prep: x -> bf16; Wq|Wk|Wv -> Wqkvb bf16 [1536][512]; biases concat; Wo -> bf16
// ---------------------------------------------------------------------------
__global__ __launch_bounds__(256)
void prep(const float* __restrict__ x,
          const float* __restrict__ Wq, const float* __restrict__ Wk,
          const float* __restrict__ Wv, const float* __restrict__ Wo,
          const float* __restrict__ bq, const float* __restrict__ bk,
          const float* __restrict__ bv,
          ushort_t* __restrict__ xb, ushort_t* __restrict__ Wqkvb,
          float* __restrict__ bqkv, ushort_t* __restrict__ Wob) {
    int t = blockIdx.x * 256 + threadIdx.x;   // f4-group index, 1048576 total
    {
        float4 v = ((const float4*)x)[t];
        uint2 p;
        p.x = f2bf(v.x) | (f2bf(v.y) << 16);
        p.y = f2bf(v.z) | (f2bf(v.w) << 16);
        ((uint2*)xb)[t] = p;
    }
    if (t < 65536) {   // 512*512/4 groups per weight
        float4 a = ((const float4*)Wq)[t];
        float4 b = ((const float4*)Wk)[t];
        float4 c = ((const float4*)Wv)[t];
        float4 d = ((const float4*)Wo)[t];
        uint2 p;
        p.x = f2bf(a.x) | (f2bf(a.y) << 16); p.y = f2bf(a.z) | (f2bf(a.w) << 16);
        ((uint2*)Wqkvb)[t] = p;
        p.x = f2bf(b.x) | (f2bf(b.y) << 16); p.y = f2bf(b.z) | (f2bf(b.w) << 16);
        ((uint2*)Wqkvb)[t + 65536] = p;
        p.x = f2bf(c.x) | (f2bf(c.y) << 16); p.y = f2bf(c.z) | (f2bf(c.w) << 16);
        ((uint2*)Wqkvb)[t + 131072] = p;
        p.x = f2bf(d.x) | (f2bf(d.y) << 16); p.y = f2bf(d.z) | (f2bf(d.w) << 16);
        ((uint2*)Wob)[t] = p;
    }
    if (t < 512) {
        bqkv[t] = bq[t]; bqkv[512 + t] = bk[t]; bqkv[1024 + t] = bv[t];
    }
}

// ---------------------------------------------------------------------------
// GEMM C[8192 x N] = A[8192x512]bf16 * BT[Nx512]bf16 + bias, 128x128 tile,
// BK=32, 4 waves, 16x16x32 mfma, 4x4 subtiles per wave.
// MODE 0: QKV (N=1536): n0<1024 -> LDS-transposed coalesced bf16 stores to
//         QKb[8192][1024] (Q cols additionally scaled by CEXP);
//         n0>=1024 -> transposed packed stores to VTg[2048][2048].
// MODE 1: out proj (N=512): LDS-transposed coalesced fp32 stores + bias.
// ---------------------------------------------------------------------------
template<int MODE>
__global__ __launch_bounds__(256)
void gemm128(const ushort_t* __restrict__ A, const ushort_t* __restrict__ BT,
             const float* __restrict__ bias, ushort_t* __restrict__ oQK,
             ushort_t* __restrict__ oVT, float* __restrict__ oC) {
    __shared__ ushort_t As[128][40];
    __shared__ ushort_t Bs[128][40];
    __shared__ float ep[32][132];   // epilogue transpose buffer (16.9 KB)
    const int tid = threadIdx.x, wave = tid >> 6, lane = tid & 63;
    const int m0 = blockIdx.x * 128, n0 = blockIdx.y * 128;
    const int wr = (wave & 1) * 64, wc = (wave >> 1) * 64;

    f32x4 acc[4][4];
#pragma unroll
    for (int i = 0; i < 4; ++i)
#pragma unroll
        for (int j = 0; j < 4; ++j) acc[i][j] = (f32x4){0.f, 0.f, 0.f, 0.f};

    const int sr = tid >> 1, sh = (tid & 1) * 16;
    const ushort_t* Arow = A + (size_t)(m0 + sr) * 512 + sh;
    const ushort_t* Brow = BT + (size_t)(n0 + sr) * 512 + sh;
    const int fr = lane & 15, fc = (lane >> 4) * 8;

    for (int kt = 0; kt < 16; ++kt) {
        uint4 a0 = *(const uint4*)(Arow + kt * 32);
        uint4 a1 = *(const uint4*)(Arow + kt * 32 + 8);
        uint4 b0 = *(const uint4*)(Brow + kt * 32);
        uint4 b1 = *(const uint4*)(Brow + kt * 32 + 8);
        __syncthreads();
        *(uint4*)&As[sr][sh] = a0;  *(uint4*)&As[sr][sh + 8] = a1;
        *(uint4*)&Bs[sr][sh] = b0;  *(uint4*)&Bs[sr][sh + 8] = b1;
        __syncthreads();
        bf16x8 af[4], bf[4];
#pragma unroll
        for (int i = 0; i < 4; ++i) af[i] = *(const bf16x8*)&As[wr + i * 16 + fr][fc];
#pragma unroll
        for (int j = 0; j < 4; ++j) bf[j] = *(const bf16x8*)&Bs[wc + j * 16 + fr][fc];
#pragma unroll
        for (int i = 0; i < 4; ++i)
#pragma unroll
            for (int j = 0; j < 4; ++j)
                acc[i][j] = __builtin_amdgcn_mfma_f32_16x16x32_bf16(af[i], bf[j], acc[i][j], 0, 0, 0);
    }

    const int col_l = lane & 15, row_l = (lane >> 4) * 4;

    if (MODE == 0 && n0 >= 1024) {
        // V part: direct transposed packed stores (unchanged)
#pragma unroll
        for (int j = 0; j < 4; ++j) {
            const int col = n0 + wc + j * 16 + col_l;
            const float bv = bias[col];
#pragma unroll
            for (int i = 0; i < 4; ++i) {
                const int row = m0 + wr + i * 16 + row_l;
                f32x4 v = acc[i][j];
                v += (f32x4){bv, bv, bv, bv};
                const int e = col - 1024;
                const int b = row >> 11, tok = row & 2047;
                uint2 p;
                p.x = f2bf(v[0]) | (f2bf(v[1]) << 16);
                p.y = f2bf(v[2]) | (f2bf(v[3]) << 16);
                *(uint2*)&oVT[((size_t)(b * 512 + e)) * 2048 + tok] = p;
            }
        }
        return;
    }

    // LDS-transposed coalesced epilogue (QK bf16 / out-proj fp32)
    const float scale = (MODE == 0 && n0 < 512) ? CEXP : 1.0f;
    float bv[4];
#pragma unroll
    for (int j = 0; j < 4; ++j) bv[j] = bias[n0 + wc + j * 16 + col_l];

    const int erow = tid >> 3, eseg = (tid & 7) * 16;
#pragma unroll
    for (int c = 0; c < 4; ++c) {
        __syncthreads();   // prior chunk (or K-loop) reads complete
        if (wr == (c >> 1) * 64) {
#pragma unroll
            for (int ii = 0; ii < 2; ++ii) {
                const int i = (c & 1) * 2 + ii;
#pragma unroll
                for (int j = 0; j < 4; ++j) {
                    f32x4 v = acc[i][j];
#pragma unroll
                    for (int r = 0; r < 4; ++r)
                        ep[ii * 16 + row_l + r][wc + j * 16 + col_l] = (v[r] + bv[j]) * scale;
                }
            }
        }
        __syncthreads();
        const int grow = m0 + c * 32 + erow;
        if (MODE == 0) {
            uint4 o0, o1;
#pragma unroll
            for (int k = 0; k < 4; ++k) {
                uint lo = f2bf(ep[erow][eseg + k * 2])     | (f2bf(ep[erow][eseg + k * 2 + 1]) << 16);
                uint hi = f2bf(ep[erow][eseg + 8 + k * 2]) | (f2bf(ep[erow][eseg + 9 + k * 2]) << 16);
                ((uint*)&o0)[k] = lo; ((uint*)&o1)[k] = hi;
            }
            *(uint4*)&oQK[(size_t)grow * 1024 + n0 + eseg]     = o0;
            *(uint4*)&oQK[(size_t)grow * 1024 + n0 + eseg + 8] = o1;
        } else {
#pragma unroll
            for (int k = 0; k < 4; ++k) {
                f32x4 v = *(const f32x4*)&ep[erow][eseg + k * 4];
                *(f32x4*)&oC[(size_t)grow * 512 + n0 + eseg + k * 4] = v;
            }
        }
    }
}

// ---------------------------------------------------------------------------
// MFMA flash attention (no max-rescale: |logit*CEXP| < ~1 provably; CEXP is
// pre-folded into Q). NSLICE-way split over K (flash-decoding).
// Block = 128 q-rows x (b,h) x kslice; wave w owns q-rows [w*32, w*32+32).
// Per 64-krow tile: S^T = K·Q^T (32x32x16), P^T = exp2(S^T) truncated to bf16
// (l sums the truncated values -> exact normalization cancellation),
// O += P·V. NSLICE>1: store unnormalized f32 O + l partials.
// ---------------------------------------------------------------------------
template<int NSLICE>
__global__ __launch_bounds__(256)
void attn_mfma(const ushort_t* __restrict__ QK, const ushort_t* __restrict__ VT,
               float* __restrict__ Op, float* __restrict__ Lp,
               ushort_t* __restrict__ AO) {
    __shared__ ushort_t Ks[64][72];       // [krow][d]
    __shared__ ushort_t Vs[64][72];       // [d][krow]  (V^T tile)
    __shared__ ushort_t Ps[4][32][72];    // per-wave [qrow][krow]
    __shared__ float ls[128];

    const int tid = threadIdx.x, w = tid >> 6, lane = tid & 63;
    const int qt = blockIdx.x, bh = blockIdx.y, b = bh >> 3, h = bh & 7;
    const int slice = (NSLICE > 1) ? blockIdx.z : 0;
    const int l31 = lane & 31, lhi = lane >> 5;

    // preload Q B-frags (16 VGPRs), reused across whole K loop (pre-scaled by CEXP)
    const size_t qrow = (size_t)(b * NSEQ + qt * 128 + w * 32 + l31);
    bf16x8 qf[4];
#pragma unroll
    for (int ks = 0; ks < 4; ++ks)
        qf[ks] = *(const bf16x8*)&QK[qrow * 1024 + h * 64 + ks * 16 + lhi * 8];

    f32x16 accO[2];
#pragma unroll
    for (int i = 0; i < 16; ++i) { accO[0][i] = 0.f; accO[1][i] = 0.f; }
    float lpart = 0.f;

    const int sr = tid & 63, sc = (tid >> 6) * 16;
    const ushort_t* Kg = QK + (size_t)(b * NSEQ) * 1024 + 512 + h * 64;
    const ushort_t* Vg = VT + ((size_t)(b * 512 + h * 64)) * 2048;

    const int kt0 = slice * (32 / NSLICE), kt1 = kt0 + 32 / NSLICE;
    for (int kt = kt0; kt < kt1; ++kt) {
        const int k0 = kt * 64;
        uint4 kv0 = *(const uint4*)&Kg[(size_t)(k0 + sr) * 1024 + sc];
        uint4 kv1 = *(const uint4*)&Kg[(size_t)(k0 + sr) * 1024 + sc + 8];
        uint4 vv0 = *(const uint4*)&Vg[(size_t)sr * 2048 + k0 + sc];
        uint4 vv1 = *(const uint4*)&Vg[(size_t)sr * 2048 + k0 + sc + 8];
        __syncthreads();                          // A: prior reads done
        *(uint4*)&Ks[sr][sc] = kv0;  *(uint4*)&Ks[sr][sc + 8] = kv1;
        *(uint4*)&Vs[sr][sc] = vv0;  *(uint4*)&Vs[sr][sc + 8] = vv1;
        __syncthreads();                          // B: tiles visible

        // S^T = K · Q^T : D[m=krow][n=qrow]  (already scaled by CEXP via Q)
        f32x16 st[2];
#pragma unroll
        for (int i = 0; i < 16; ++i) { st[0][i] = 0.f; st[1][i] = 0.f; }
#pragma unroll
        for (int ks = 0; ks < 4; ++ks) {
            bf16x8 ka0 = *(const bf16x8*)&Ks[l31][ks * 16 + lhi * 8];
            bf16x8 ka1 = *(const bf16x8*)&Ks[32 + l31][ks * 16 + lhi * 8];
            st[0] = __builtin_amdgcn_mfma_f32_32x32x16_bf16(ka0, qf[ks], st[0], 0, 0, 0);
            st[1] = __builtin_amdgcn_mfma_f32_32x32x16_bf16(ka1, qf[ks], st[1], 0, 0, 0);
        }

        // P^T = exp2(S^T); truncate to bf16, sum truncated values for l
#pragma unroll
        for (int ms = 0; ms < 2; ++ms) {
#pragma unroll
            for (int g = 0; g < 4; ++g) {
                uint u0 = __builtin_bit_cast(uint, __builtin_amdgcn_exp2f(st[ms][g * 4 + 0]));
                uint u1 = __builtin_bit_cast(uint, __builtin_amdgcn_exp2f(st[ms][g * 4 + 1]));
                uint u2 = __builtin_bit_cast(uint, __builtin_amdgcn_exp2f(st[ms][g * 4 + 2]));
                uint u3 = __builtin_bit_cast(uint, __builtin_amdgcn_exp2f(st[ms][g * 4 + 3]));
                lpart += __builtin_bit_cast(float, u0 & 0xffff0000u)
                       + __builtin_bit_cast(float, u1 & 0xffff0000u)
                       + __builtin_bit_cast(float, u2 & 0xffff0000u)
                       + __builtin_bit_cast(float, u3 & 0xffff0000u);
                uint2 p;
                p.x = (u0 >> 16) | (u1 & 0xffff0000u);
                p.y = (u2 >> 16) | (u3 & 0xffff0000u);
                *(uint2*)&Ps[w][l31][ms * 32 + g * 8 + lhi * 4] = p;
            }
        }
        // NO barrier: Ps[w] is wave-private (lgkmcnt ordering suffices)

        // O += P · V : D[m=qrow][n=d]
#pragma unroll
        for (int ks = 0; ks < 4; ++ks) {
            bf16x8 pa  = *(const bf16x8*)&Ps[w][l31][ks * 16 + lhi * 8];
            bf16x8 vb0 = *(const bf16x8*)&Vs[l31][ks * 16 + lhi * 8];
            bf16x8 vb1 = *(const bf16x8*)&Vs[32 + l31][ks * 16 + lhi * 8];
            accO[0] = __builtin_amdgcn_mfma_f32_32x32x16_bf16(pa, vb0, accO[0], 0, 0, 0);
            accO[1] = __builtin_amdgcn_mfma_f32_32x32x16_bf16(pa, vb1, accO[1], 0, 0, 0);
        }
    }

    float lfull = lpart + __shfl_xor(lpart, 32);

    if (NSLICE == 1) {
        if (lane < 32) ls[w * 32 + l31] = lfull;
        __syncthreads();
#pragma unroll
        for (int g = 0; g < 4; ++g) {
            float4 lv = *(const float4*)&ls[w * 32 + g * 8 + lhi * 4];
#pragma unroll
            for (int r = 0; r < 4; ++r) {
                const float inv = 1.0f / ((const float*)&lv)[r];
                const int rowp = g * 8 + lhi * 4 + r;
                const size_t orow = (size_t)(b * NSEQ + qt * 128 + w * 32 + rowp);
                AO[orow * 512 + h * 64 + l31]      = (ushort_t)f2bf(accO[0][g * 4 + r] * inv);
                AO[orow * 512 + h * 64 + 32 + l31] = (ushort_t)f2bf(accO[1][g * 4 + r] * inv);
            }
        }
    } else {
        const size_t rowbase = (size_t)(b * NSEQ + qt * 128 + w * 32);
        if (lane < 32) Lp[(size_t)slice * 65536 + (rowbase + l31) * 8 + h] = lfull;
        float* Os = Op + (size_t)slice * 4194304;
#pragma unroll
        for (int g = 0; g < 4; ++g) {
#pragma unroll
            for (int r = 0; r < 4; ++r) {
                const int rowp = g * 8 + lhi * 4 + r;
                const size_t orow = rowbase + rowp;
                Os[orow * 512 + h * 64 + l31]      = accO[0][g * 4 + r];
                Os[orow * 512 + h * 64 + 32 + l31] = accO[1][g * 4 + r];
            }
        }
    }
}

// ---------------------------------------------------------------------------
// Combine split-K partials: AO = (O0+O1) / (l0+l1), bf16.
// ---------------------------------------------------------------------------
__global__ __launch_bounds__(256)
void combine2(const float* __restrict__ Op, const float* __restrict__ Lp,
              ushort_t* __restrict__ AO) {
    const int t = blockIdx.x * 256 + threadIdx.x;   // 0..1048575
    const int row = t >> 7;
    const int c4  = (t & 127) * 4;
    const int h = c4 >> 6;
    float4 a = ((const float4*)Op)[t];
    float4 b = ((const float4*)(Op + 4194304))[t];
    const float inv = 1.0f / (Lp[row * 8 + h] + Lp[65536 + row * 8 + h]);
    uint2 p;
    p.x = f2bf((a.x + b.x) * inv) | (f2bf((a.y + b.y) * inv) << 16);
    p.y = f2bf((a.z + b.z) * inv) | (f2bf((a.w + b.w) * inv) << 16);
    ((uint2*)AO)[t] = p;
}

// ---------------------------------------------------------------------------
extern "C" void kernel_launch(void* const* d_in, const int* in_sizes, int n_in,
                              void* d_out, int out_size, void* d_ws, size_t ws_size,
                              hipStream_t stream) {
    const float* x  = (const float*)d_in[0];
    const float* Wq = (const float*)d_in[1];
    const float* bq = (const float*)d_in[2];
    const float* Wk = (const float*)d_in[3];
    const float* bk = (const float*)d_in[4];
    const float* Wv = (const float*)d_in[5];
    const float* bv = (const float*)d_in[6];
    const float* Wo = (const float*)d_in[7];
    const float* bo = (const float*)d_in[8];

    char* ws = (char*)d_ws;
    ushort_t* xb    = (ushort_t*)(ws);                       //  8,388,608 B
    ushort_t* Wqkvb = (ushort_t*)(ws + 8388608);             //  1,572,864 B
    ushort_t* Wob   = (ushort_t*)(ws + 9961472);             //    524,288 B
    float*    bqkv  = (float*)   (ws + 10485760);            //      6,144 B
    ushort_t* QKb   = (ushort_t*)(ws + 10491904);            // 16,777,216 B
    ushort_t* VTg   = (ushort_t*)(ws + 27269120);            //  8,388,608 B
    ushort_t* AOb   = (ushort_t*)(ws + 35657728);            //  8,388,608 B
    float*    Opart = (float*)   (ws + 44046336);            // 33,554,432 B
    float*    Lpart = (float*)   (ws + 77600768);            //    524,288 B
    const bool split = ws_size >= 78125056;

    prep<<<4096, 256, 0, stream>>>(x, Wq, Wk, Wv, Wo, bq, bk, bv,
                                   xb, Wqkvb, bqkv, Wob);
    gemm128<0><<<dim3(64, 12), 256, 0, stream>>>(xb, Wqkvb, bqkv, QKb, VTg, nullptr);
    if (split) {
        attn_mfma<2><<<dim3(16, 32, 2), 256, 0, stream>>>(QKb, VTg, Opart, Lpart, nullptr);
        combine2<<<4096, 256, 0, stream>>>(Opart, Lpart, AOb);
    } else {
        attn_mfma<1><<<dim3(16, 32), 256, 0, stream>>>(QKb, VTg, nullptr, nullptr, AOb);
    }
    gemm128<1><<<dim3(64, 4), 256, 0, stream>>>(AOb, Wob, bo, nullptr, nullptr, (float*)d_out);
}